// Round 7
// baseline (525.846 us; speedup 1.0000x reference)
//
#include <hip/hip_runtime.h>
#include <hip/hip_bf16.h>

#define S_LEN 4096
#define DMODEL 512
#define NHEADS 8
#define HDIM 64

typedef __hip_bfloat16 bf16;
typedef __attribute__((ext_vector_type(8))) short bf16x8;
typedef __attribute__((ext_vector_type(4))) float f32x4;
typedef __attribute__((ext_vector_type(4))) _Float16 f16x4;
typedef __attribute__((ext_vector_type(8))) _Float16 f16x8;

__device__ __forceinline__ f32x4 mfma16x16x32(bf16x8 a, bf16x8 b, f32x4 c) {
    return __builtin_amdgcn_mfma_f32_16x16x32_bf16(a, b, c, 0, 0, 0);
}
__device__ __forceinline__ f32x4 mfma16x16x16h(f16x4 a, f16x4 b, f32x4 c) {
    return __builtin_amdgcn_mfma_f32_16x16x16f16(a, b, c, 0, 0, 0);
}

// Q scale folded with log2(e) so softmax uses exp2 (bare v_exp_f32)
#define QSCALE (0.125f * 1.44269504088896f)

// ---------------------------------------------------------------------------
// fp32 -> bf16 elementwise convert (X matrix)
// ---------------------------------------------------------------------------
__global__ __launch_bounds__(256) void cvt_f32_bf16(
    const float* __restrict__ in, bf16* __restrict__ out, int n)
{
    int i = (blockIdx.x * 256 + threadIdx.x) * 8;
    if (i >= n) return;
    float4 a = *(const float4*)(in + i);
    float4 b = *(const float4*)(in + i + 4);
    bf16 tmp[8];
    tmp[0] = __float2bfloat16(a.x); tmp[1] = __float2bfloat16(a.y);
    tmp[2] = __float2bfloat16(a.z); tmp[3] = __float2bfloat16(a.w);
    tmp[4] = __float2bfloat16(b.x); tmp[5] = __float2bfloat16(b.y);
    tmp[6] = __float2bfloat16(b.z); tmp[7] = __float2bfloat16(b.w);
    *(bf16x8*)(out + i) = *(bf16x8*)tmp;
}

// ---------------------------------------------------------------------------
// Transpose+convert 4 512x512 fp32 weight matrices: out[n][k] = (bf16)in[k][n]
// ---------------------------------------------------------------------------
__global__ __launch_bounds__(256) void transpose_w(
    const float* __restrict__ Wq, const float* __restrict__ Wk,
    const float* __restrict__ Wv, const float* __restrict__ Wo,
    bf16* __restrict__ out)
{
    const float* src = (blockIdx.z == 0) ? Wq : (blockIdx.z == 1) ? Wk
                     : (blockIdx.z == 2) ? Wv : Wo;
    bf16* dst = out + (size_t)blockIdx.z * DMODEL * DMODEL;
    __shared__ bf16 tile[32][33];
    int tx = threadIdx.x, ty = threadIdx.y;
    int x = blockIdx.x * 32 + tx;
    int y0 = blockIdx.y * 32;
    #pragma unroll
    for (int i = ty; i < 32; i += 8)
        tile[i][tx] = __float2bfloat16(src[(size_t)(y0 + i) * DMODEL + x]);
    __syncthreads();
    int xo = y0 + tx;
    #pragma unroll
    for (int i = ty; i < 32; i += 8)
        dst[(size_t)(blockIdx.x * 32 + i) * DMODEL + xo] = tile[tx][i];
}

// ---------------------------------------------------------------------------
// Fused QKV projection: Y = X[4096,512] @ Wt[1536,512]^T, 64x64 tiles.
// ---------------------------------------------------------------------------
__global__ __launch_bounds__(256) void gemm_qkv(
    const bf16* __restrict__ A, const bf16* __restrict__ Bt,
    bf16* __restrict__ Qm, bf16* __restrict__ Km, _Float16* __restrict__ Vt)
{
    __shared__ __align__(16) bf16 abuf[64][72];
    __shared__ __align__(16) bf16 bbuf[64][72];
    const int m0 = blockIdx.x * 64, n0 = blockIdx.y * 64;
    const int t = threadIdx.x, lane = t & 63, w = t >> 6;
    const int lr = lane & 15, lq = lane >> 4;

    f32x4 acc[4] = {f32x4{0,0,0,0}, f32x4{0,0,0,0}, f32x4{0,0,0,0}, f32x4{0,0,0,0}};

    for (int k0 = 0; k0 < DMODEL; k0 += 64) {
        __syncthreads();
        #pragma unroll
        for (int i = 0; i < 2; ++i) {
            int c = t + i * 256;
            int r = c >> 3, co = (c & 7) * 8;
            *(bf16x8*)&abuf[r][co] =
                *(const bf16x8*)(A + (size_t)(m0 + r) * DMODEL + k0 + co);
            *(bf16x8*)&bbuf[r][co] =
                *(const bf16x8*)(Bt + (size_t)(n0 + r) * DMODEL + k0 + co);
        }
        __syncthreads();
        bf16x8 a0 = *(const bf16x8*)&abuf[w * 16 + lr][lq * 8];
        bf16x8 a1 = *(const bf16x8*)&abuf[w * 16 + lr][32 + lq * 8];
        #pragma unroll
        for (int nt = 0; nt < 4; ++nt) {
            bf16x8 b0 = *(const bf16x8*)&bbuf[nt * 16 + lr][lq * 8];
            bf16x8 b1 = *(const bf16x8*)&bbuf[nt * 16 + lr][32 + lq * 8];
            acc[nt] = mfma16x16x32(a0, b0, acc[nt]);
            acc[nt] = mfma16x16x32(a1, b1, acc[nt]);
        }
    }
    const int which = n0 >> 9;          // 0=Q 1=K 2=V
    const int nloc0 = n0 & 511;
    if (which == 0) {
        #pragma unroll
        for (int nt = 0; nt < 4; ++nt)
            #pragma unroll
            for (int r = 0; r < 4; ++r)
                Qm[(size_t)(m0 + w * 16 + lq * 4 + r) * DMODEL + nloc0 + nt * 16 + lr] =
                    __float2bfloat16(acc[nt][r] * QSCALE);
    } else if (which == 1) {
        #pragma unroll
        for (int nt = 0; nt < 4; ++nt)
            #pragma unroll
            for (int r = 0; r < 4; ++r)
                Km[(size_t)(m0 + w * 16 + lq * 4 + r) * DMODEL + nloc0 + nt * 16 + lr] =
                    __float2bfloat16(acc[nt][r]);
    } else {
        // LDS transpose -> coalesced V^T stores
        __syncthreads();
        _Float16* tb = (_Float16*)abuf;   // reuse as [64][72] f16
        #pragma unroll
        for (int nt = 0; nt < 4; ++nt)
            #pragma unroll
            for (int r = 0; r < 4; ++r)
                tb[(w * 16 + lq * 4 + r) * 72 + nt * 16 + lr] = (_Float16)acc[nt][r];
        __syncthreads();
        int c = t >> 2, seg = t & 3;
        _Float16 tmp[16];
        #pragma unroll
        for (int j = 0; j < 16; ++j)
            tmp[j] = tb[(seg * 16 + j) * 72 + c];
        _Float16* vp = Vt + (size_t)(nloc0 + c) * S_LEN + m0 + seg * 16;
        *(f16x8*)vp = *(f16x8*)tmp;
        *(f16x8*)(vp + 8) = *(f16x8*)(tmp + 8);
    }
}

// ---------------------------------------------------------------------------
// Out projection: out = AO[4096,512] @ Wot[512,512]^T + bias, fp32 out.
// ---------------------------------------------------------------------------
__global__ __launch_bounds__(256) void gemm_out(
    const bf16* __restrict__ A, const bf16* __restrict__ Bt,
    float* __restrict__ Out, const float* __restrict__ bias)
{
    __shared__ __align__(16) bf16 abuf[64][72];
    __shared__ __align__(16) bf16 bbuf[64][72];
    const int m0 = blockIdx.x * 64, n0 = blockIdx.y * 64;
    const int t = threadIdx.x, lane = t & 63, w = t >> 6;
    const int lr = lane & 15, lq = lane >> 4;

    f32x4 acc[4] = {f32x4{0,0,0,0}, f32x4{0,0,0,0}, f32x4{0,0,0,0}, f32x4{0,0,0,0}};

    for (int k0 = 0; k0 < DMODEL; k0 += 64) {
        __syncthreads();
        #pragma unroll
        for (int i = 0; i < 2; ++i) {
            int c = t + i * 256;
            int r = c >> 3, co = (c & 7) * 8;
            *(bf16x8*)&abuf[r][co] =
                *(const bf16x8*)(A + (size_t)(m0 + r) * DMODEL + k0 + co);
            *(bf16x8*)&bbuf[r][co] =
                *(const bf16x8*)(Bt + (size_t)(n0 + r) * DMODEL + k0 + co);
        }
        __syncthreads();
        bf16x8 a0 = *(const bf16x8*)&abuf[w * 16 + lr][lq * 8];
        bf16x8 a1 = *(const bf16x8*)&abuf[w * 16 + lr][32 + lq * 8];
        #pragma unroll
        for (int nt = 0; nt < 4; ++nt) {
            bf16x8 b0 = *(const bf16x8*)&bbuf[nt * 16 + lr][lq * 8];
            bf16x8 b1 = *(const bf16x8*)&bbuf[nt * 16 + lr][32 + lq * 8];
            acc[nt] = mfma16x16x32(a0, b0, acc[nt]);
            acc[nt] = mfma16x16x32(a1, b1, acc[nt]);
        }
    }
    #pragma unroll
    for (int nt = 0; nt < 4; ++nt)
        #pragma unroll
        for (int r = 0; r < 4; ++r)
            Out[(size_t)(m0 + w * 16 + lq * 4 + r) * DMODEL + n0 + nt * 16 + lr] =
                acc[nt][r] + bias[n0 + nt * 16 + lr];
}

// ---------------------------------------------------------------------------
// Attention v4: Q-tile 64, 4 qt/wave (round-5 reuse), kt-split across 2
// BLOCKS (grid 1024 = h x split x qb) -> 4 blocks/CU TLP. Each wave: 8 kt
// iters (kt = w + 32*s + 4*i), K/V via incremented pointers (cheap addr
// VALU), no LDS in main loop. exp2-no-max softmax => split partials combine
// linearly: block stores partial O (f32) + partial l; `combine` kernel
// finishes. In-block 4-wave combine: 3-round rotating 16KB LDS exchange.
// ---------------------------------------------------------------------------
__global__ __launch_bounds__(256, 4) void attn_kernel(
    const bf16* __restrict__ Q, const bf16* __restrict__ Kmat,
    const _Float16* __restrict__ Vt, float* __restrict__ AOp,
    float* __restrict__ Lp)
{
    __shared__ __align__(16) float cbuf[2][4][4][64][4];  // 32 KB
    __shared__ float lbuf[4][4][16];                      // 1 KB

    const int h = blockIdx.x & 7;
    const int s = (blockIdx.x >> 3) & 1;
    const int qb = blockIdx.x >> 4;
    const int t = threadIdx.x, lane = t & 63, w = t >> 6;
    const int lr = lane & 15, lq = lane >> 4;
    const int q0 = qb * 64;

    // Q B-frags for 4 qt tiles (B[n=lr][k=lq*8+j])
    bf16x8 qf[4][2];
    #pragma unroll
    for (int qt = 0; qt < 4; ++qt) {
        const bf16* qp = Q + (size_t)(q0 + qt * 16 + lr) * DMODEL + h * HDIM + lq * 8;
        qf[qt][0] = *(const bf16x8*)qp;
        qf[qt][1] = *(const bf16x8*)(qp + 32);
    }

    // incremented pointers: K per mt, V per ht
    const int kt0 = w + 32 * s;
    const bf16* kp[4];
    const _Float16* vp[4];
    #pragma unroll
    for (int mt = 0; mt < 4; ++mt)
        kp[mt] = Kmat + (size_t)(kt0 * 64 + mt * 16 + lr) * DMODEL + h * HDIM + lq * 8;
    #pragma unroll
    for (int ht = 0; ht < 4; ++ht)
        vp[ht] = Vt + (size_t)(h * HDIM + ht * 16 + lr) * S_LEN + kt0 * 64 + lq * 4;
    const size_t kstep = (size_t)4 * 64 * DMODEL;   // 4 kt tiles of rows
    const size_t vstep = 4 * 64;                    // 4 kt tiles of cols

    f32x4 oacc[4][4];   // [qt][ht]; C: row(Q)=lq*4+r, col(hd)=lr
    #pragma unroll
    for (int i = 0; i < 4; ++i)
        #pragma unroll
        for (int j = 0; j < 4; ++j) oacc[i][j] = f32x4{0, 0, 0, 0};
    float lsum[4] = {0, 0, 0, 0};

    for (int i = 0; i < 8; ++i) {
        // K A-frags (A[m=lr][k=lq*8+j])
        bf16x8 kf[4][2];
        #pragma unroll
        for (int mt = 0; mt < 4; ++mt) {
            kf[mt][0] = *(const bf16x8*)kp[mt];
            kf[mt][1] = *(const bf16x8*)(kp[mt] + 32);
        }
        // V^T B-frags (B[n=hd=lr][k=Kidx=lq*4+j])
        f16x4 vf[4][4];   // [mt][ht]
        #pragma unroll
        for (int ht = 0; ht < 4; ++ht)
            #pragma unroll
            for (int mt = 0; mt < 4; ++mt)
                vf[mt][ht] = *(const f16x4*)(vp[ht] + mt * 16);

        #pragma unroll
        for (int qt = 0; qt < 4; ++qt) {
            f32x4 st[4];
            #pragma unroll
            for (int mt = 0; mt < 4; ++mt) {
                f32x4 z = {0, 0, 0, 0};
                z = mfma16x16x32(kf[mt][0], qf[qt][0], z);
                z = mfma16x16x32(kf[mt][1], qf[qt][1], z);
                st[mt] = z;
            }
            // P = exp2(S^T); A-frag of 16x16x16: A[m=Q=lr][k=lq*4+r]
            f16x4 pf[4];
            #pragma unroll
            for (int mt = 0; mt < 4; ++mt)
                #pragma unroll
                for (int r = 0; r < 4; ++r) {
                    float p = exp2f(st[mt][r]);
                    lsum[qt] += p;
                    pf[mt][r] = (_Float16)p;
                }
            #pragma unroll
            for (int mt = 0; mt < 4; ++mt)
                #pragma unroll
                for (int ht = 0; ht < 4; ++ht)
                    oacc[qt][ht] = mfma16x16x16h(pf[mt], vf[mt][ht], oacc[qt][ht]);
        }

        #pragma unroll
        for (int mt = 0; mt < 4; ++mt) kp[mt] += kstep;
        #pragma unroll
        for (int ht = 0; ht < 4; ++ht) vp[ht] += vstep;
    }

    // ---- l partials: reduce over lq groups, publish ----
    #pragma unroll
    for (int qt = 0; qt < 4; ++qt) {
        float v = lsum[qt];
        v += __shfl_xor(v, 16);
        v += __shfl_xor(v, 32);
        if (lq == 0) lbuf[w][qt][lr] = v;
    }

    // ---- 3-round rotating O exchange: wave w ends owning qt == w ----
    #pragma unroll
    for (int r = 1; r < 4; ++r) {
        int src = (w + r) & 3;
        #pragma unroll
        for (int ht = 0; ht < 4; ++ht)
            *(f32x4*)&cbuf[r & 1][w][ht][lane][0] = oacc[src][ht];
        __syncthreads();
        int from = (w - r) & 3;
        #pragma unroll
        for (int ht = 0; ht < 4; ++ht)
            oacc[w][ht] += *(const f32x4*)&cbuf[r & 1][from][ht][lane][0];
    }

    // ---- store split-partial O (f32) + split-partial l ----
    float* aop = AOp + (size_t)s * S_LEN * DMODEL;
    #pragma unroll
    for (int r = 0; r < 4; ++r) {
        int row = q0 + w * 16 + lq * 4 + r;
        #pragma unroll
        for (int ht = 0; ht < 4; ++ht)
            aop[(size_t)row * DMODEL + h * HDIM + ht * 16 + lr] = oacc[w][ht][r];
    }
    if (lq == 0) {
        float lt = lbuf[0][w][lr] + lbuf[1][w][lr] + lbuf[2][w][lr] + lbuf[3][w][lr];
        Lp[(size_t)s * NHEADS * S_LEN + (size_t)h * S_LEN + q0 + w * 16 + lr] = lt;
    }
}

// ---------------------------------------------------------------------------
// Combine the two kt-splits: AO = bf16( (O0+O1) / (l0+l1) )
// ---------------------------------------------------------------------------
__global__ __launch_bounds__(256) void combine(
    const float* __restrict__ AOp, const float* __restrict__ Lp,
    bf16* __restrict__ AO)
{
    int i = (blockIdx.x * 256 + threadIdx.x) * 8;
    int row = i >> 9, col = i & 511, h = col >> 6;
    float l0 = Lp[(size_t)h * S_LEN + row];
    float l1 = Lp[(size_t)NHEADS * S_LEN + (size_t)h * S_LEN + row];
    float linv = 1.0f / (l0 + l1);
    const float* p0 = AOp + i;
    const float* p1 = AOp + (size_t)S_LEN * DMODEL + i;
    float4 a0 = *(const float4*)p0;
    float4 a1 = *(const float4*)(p0 + 4);
    float4 b0 = *(const float4*)p1;
    float4 b1 = *(const float4*)(p1 + 4);
    bf16 tmp[8];
    tmp[0] = __float2bfloat16((a0.x + b0.x) * linv);
    tmp[1] = __float2bfloat16((a0.y + b0.y) * linv);
    tmp[2] = __float2bfloat16((a0.z + b0.z) * linv);
    tmp[3] = __float2bfloat16((a0.w + b0.w) * linv);
    tmp[4] = __float2bfloat16((a1.x + b1.x) * linv);
    tmp[5] = __float2bfloat16((a1.y + b1.y) * linv);
    tmp[6] = __float2bfloat16((a1.z + b1.z) * linv);
    tmp[7] = __float2bfloat16((a1.w + b1.w) * linv);
    *(bf16x8*)(AO + i) = *(bf16x8*)tmp;
}

// ---------------------------------------------------------------------------
extern "C" void kernel_launch(void* const* d_in, const int* in_sizes, int n_in,
                              void* d_out, int out_size, void* d_ws, size_t ws_size,
                              hipStream_t stream) {
    const float* X  = (const float*)d_in[0];
    const float* Wq = (const float*)d_in[1];
    const float* Wk = (const float*)d_in[2];
    const float* Wv = (const float*)d_in[3];
    const float* Wo = (const float*)d_in[4];
    const float* bo = (const float*)d_in[5];
    float* out = (float*)d_out;

    char* ws = (char*)d_ws;
    bf16* Wt = (bf16*)ws;                                  // [4][512][512] bf16
    bf16* Xb = (bf16*)(ws + (size_t)4 * DMODEL * DMODEL * 2);
    bf16* Qm = Xb + (size_t)S_LEN * DMODEL;
    bf16* Km = Qm + (size_t)S_LEN * DMODEL;
    _Float16* Vt = (_Float16*)(Km + (size_t)S_LEN * DMODEL);   // [512][4096] f16
    bf16* AO = (bf16*)(Vt + (size_t)S_LEN * DMODEL);
    float* AOp = (float*)(AO + (size_t)S_LEN * DMODEL);        // [2][4096][512] f32
    float* Lp  = AOp + (size_t)2 * S_LEN * DMODEL;             // [2][8][4096] f32

    bf16* Wot = Wt + (size_t)3 * DMODEL * DMODEL;

    int nX = S_LEN * DMODEL;
    cvt_f32_bf16<<<nX / (256 * 8), 256, 0, stream>>>(X, Xb, nX);
    transpose_w<<<dim3(16, 16, 4), dim3(32, 8), 0, stream>>>(Wq, Wk, Wv, Wo, Wt);

    gemm_qkv<<<dim3(S_LEN / 64, 3 * DMODEL / 64), 256, 0, stream>>>(
        Xb, Wt, Qm, Km, Vt);

    attn_kernel<<<1024, 256, 0, stream>>>(Qm, Km, Vt, AOp, Lp);
    combine<<<S_LEN * DMODEL / (256 * 8), 256, 0, stream>>>(AOp, Lp, AO);

    gemm_out<<<dim3(S_LEN / 64, DMODEL / 64), 256, 0, stream>>>(AO, Wot, out, bo);
}

// Round 9
// 297.791 us; speedup vs baseline: 1.7658x; 1.7658x over previous
//
#include <hip/hip_runtime.h>
#include <hip/hip_bf16.h>

#define S_LEN 4096
#define DMODEL 512
#define NHEADS 8
#define HDIM 64

typedef __hip_bfloat16 bf16;
typedef __attribute__((ext_vector_type(8))) short bf16x8;
typedef __attribute__((ext_vector_type(4))) float f32x4;
typedef __attribute__((ext_vector_type(4))) _Float16 f16x4;
typedef __attribute__((ext_vector_type(8))) _Float16 f16x8;

__device__ __forceinline__ f32x4 mfma16x16x32(bf16x8 a, bf16x8 b, f32x4 c) {
    return __builtin_amdgcn_mfma_f32_16x16x32_bf16(a, b, c, 0, 0, 0);
}
__device__ __forceinline__ f32x4 mfma16x16x16h(f16x4 a, f16x4 b, f32x4 c) {
    return __builtin_amdgcn_mfma_f32_16x16x16f16(a, b, c, 0, 0, 0);
}

// Q scale folded with log2(e) so softmax uses exp2 (bare v_exp_f32)
#define QSCALE (0.125f * 1.44269504088896f)

// ---------------------------------------------------------------------------
// fp32 -> bf16 elementwise convert (X matrix)
// ---------------------------------------------------------------------------
__global__ __launch_bounds__(256) void cvt_f32_bf16(
    const float* __restrict__ in, bf16* __restrict__ out, int n)
{
    int i = (blockIdx.x * 256 + threadIdx.x) * 8;
    if (i >= n) return;
    float4 a = *(const float4*)(in + i);
    float4 b = *(const float4*)(in + i + 4);
    bf16 tmp[8];
    tmp[0] = __float2bfloat16(a.x); tmp[1] = __float2bfloat16(a.y);
    tmp[2] = __float2bfloat16(a.z); tmp[3] = __float2bfloat16(a.w);
    tmp[4] = __float2bfloat16(b.x); tmp[5] = __float2bfloat16(b.y);
    tmp[6] = __float2bfloat16(b.z); tmp[7] = __float2bfloat16(b.w);
    *(bf16x8*)(out + i) = *(bf16x8*)tmp;
}

// ---------------------------------------------------------------------------
// Transpose+convert 4 512x512 fp32 weight matrices: out[n][k] = (bf16)in[k][n]
// ---------------------------------------------------------------------------
__global__ __launch_bounds__(256) void transpose_w(
    const float* __restrict__ Wq, const float* __restrict__ Wk,
    const float* __restrict__ Wv, const float* __restrict__ Wo,
    bf16* __restrict__ out)
{
    const float* src = (blockIdx.z == 0) ? Wq : (blockIdx.z == 1) ? Wk
                     : (blockIdx.z == 2) ? Wv : Wo;
    bf16* dst = out + (size_t)blockIdx.z * DMODEL * DMODEL;
    __shared__ bf16 tile[32][33];
    int tx = threadIdx.x, ty = threadIdx.y;
    int x = blockIdx.x * 32 + tx;
    int y0 = blockIdx.y * 32;
    #pragma unroll
    for (int i = ty; i < 32; i += 8)
        tile[i][tx] = __float2bfloat16(src[(size_t)(y0 + i) * DMODEL + x]);
    __syncthreads();
    int xo = y0 + tx;
    #pragma unroll
    for (int i = ty; i < 32; i += 8)
        dst[(size_t)(blockIdx.x * 32 + i) * DMODEL + xo] = tile[tx][i];
}

// ---------------------------------------------------------------------------
// Fused QKV projection: Y = X[4096,512] @ Wt[1536,512]^T, 64x64 tiles.
// ---------------------------------------------------------------------------
__global__ __launch_bounds__(256) void gemm_qkv(
    const bf16* __restrict__ A, const bf16* __restrict__ Bt,
    bf16* __restrict__ Qm, bf16* __restrict__ Km, _Float16* __restrict__ Vt)
{
    __shared__ __align__(16) bf16 abuf[64][72];
    __shared__ __align__(16) bf16 bbuf[64][72];
    const int m0 = blockIdx.x * 64, n0 = blockIdx.y * 64;
    const int t = threadIdx.x, lane = t & 63, w = t >> 6;
    const int lr = lane & 15, lq = lane >> 4;

    f32x4 acc[4] = {f32x4{0,0,0,0}, f32x4{0,0,0,0}, f32x4{0,0,0,0}, f32x4{0,0,0,0}};

    for (int k0 = 0; k0 < DMODEL; k0 += 64) {
        __syncthreads();
        #pragma unroll
        for (int i = 0; i < 2; ++i) {
            int c = t + i * 256;
            int r = c >> 3, co = (c & 7) * 8;
            *(bf16x8*)&abuf[r][co] =
                *(const bf16x8*)(A + (size_t)(m0 + r) * DMODEL + k0 + co);
            *(bf16x8*)&bbuf[r][co] =
                *(const bf16x8*)(Bt + (size_t)(n0 + r) * DMODEL + k0 + co);
        }
        __syncthreads();
        bf16x8 a0 = *(const bf16x8*)&abuf[w * 16 + lr][lq * 8];
        bf16x8 a1 = *(const bf16x8*)&abuf[w * 16 + lr][32 + lq * 8];
        #pragma unroll
        for (int nt = 0; nt < 4; ++nt) {
            bf16x8 b0 = *(const bf16x8*)&bbuf[nt * 16 + lr][lq * 8];
            bf16x8 b1 = *(const bf16x8*)&bbuf[nt * 16 + lr][32 + lq * 8];
            acc[nt] = mfma16x16x32(a0, b0, acc[nt]);
            acc[nt] = mfma16x16x32(a1, b1, acc[nt]);
        }
    }
    const int which = n0 >> 9;          // 0=Q 1=K 2=V
    const int nloc0 = n0 & 511;
    if (which == 0) {
        #pragma unroll
        for (int nt = 0; nt < 4; ++nt)
            #pragma unroll
            for (int r = 0; r < 4; ++r)
                Qm[(size_t)(m0 + w * 16 + lq * 4 + r) * DMODEL + nloc0 + nt * 16 + lr] =
                    __float2bfloat16(acc[nt][r] * QSCALE);
    } else if (which == 1) {
        #pragma unroll
        for (int nt = 0; nt < 4; ++nt)
            #pragma unroll
            for (int r = 0; r < 4; ++r)
                Km[(size_t)(m0 + w * 16 + lq * 4 + r) * DMODEL + nloc0 + nt * 16 + lr] =
                    __float2bfloat16(acc[nt][r]);
    } else {
        // LDS transpose -> coalesced V^T stores
        __syncthreads();
        _Float16* tb = (_Float16*)abuf;   // reuse as [64][72] f16
        #pragma unroll
        for (int nt = 0; nt < 4; ++nt)
            #pragma unroll
            for (int r = 0; r < 4; ++r)
                tb[(w * 16 + lq * 4 + r) * 72 + nt * 16 + lr] = (_Float16)acc[nt][r];
        __syncthreads();
        int c = t >> 2, seg = t & 3;
        _Float16 tmp[16];
        #pragma unroll
        for (int j = 0; j < 16; ++j)
            tmp[j] = tb[(seg * 16 + j) * 72 + c];
        _Float16* vp = Vt + (size_t)(nloc0 + c) * S_LEN + m0 + seg * 16;
        *(f16x8*)vp = *(f16x8*)tmp;
        *(f16x8*)(vp + 8) = *(f16x8*)(tmp + 8);
    }
}

// ---------------------------------------------------------------------------
// Out projection: out = AO[4096,512] @ Wot[512,512]^T + bias, fp32 out.
// ---------------------------------------------------------------------------
__global__ __launch_bounds__(256) void gemm_out(
    const bf16* __restrict__ A, const bf16* __restrict__ Bt,
    float* __restrict__ Out, const float* __restrict__ bias)
{
    __shared__ __align__(16) bf16 abuf[64][72];
    __shared__ __align__(16) bf16 bbuf[64][72];
    const int m0 = blockIdx.x * 64, n0 = blockIdx.y * 64;
    const int t = threadIdx.x, lane = t & 63, w = t >> 6;
    const int lr = lane & 15, lq = lane >> 4;

    f32x4 acc[4] = {f32x4{0,0,0,0}, f32x4{0,0,0,0}, f32x4{0,0,0,0}, f32x4{0,0,0,0}};

    for (int k0 = 0; k0 < DMODEL; k0 += 64) {
        __syncthreads();
        #pragma unroll
        for (int i = 0; i < 2; ++i) {
            int c = t + i * 256;
            int r = c >> 3, co = (c & 7) * 8;
            *(bf16x8*)&abuf[r][co] =
                *(const bf16x8*)(A + (size_t)(m0 + r) * DMODEL + k0 + co);
            *(bf16x8*)&bbuf[r][co] =
                *(const bf16x8*)(Bt + (size_t)(n0 + r) * DMODEL + k0 + co);
        }
        __syncthreads();
        bf16x8 a0 = *(const bf16x8*)&abuf[w * 16 + lr][lq * 8];
        bf16x8 a1 = *(const bf16x8*)&abuf[w * 16 + lr][32 + lq * 8];
        #pragma unroll
        for (int nt = 0; nt < 4; ++nt) {
            bf16x8 b0 = *(const bf16x8*)&bbuf[nt * 16 + lr][lq * 8];
            bf16x8 b1 = *(const bf16x8*)&bbuf[nt * 16 + lr][32 + lq * 8];
            acc[nt] = mfma16x16x32(a0, b0, acc[nt]);
            acc[nt] = mfma16x16x32(a1, b1, acc[nt]);
        }
    }
    #pragma unroll
    for (int nt = 0; nt < 4; ++nt)
        #pragma unroll
        for (int r = 0; r < 4; ++r)
            Out[(size_t)(m0 + w * 16 + lq * 4 + r) * DMODEL + n0 + nt * 16 + lr] =
                acc[nt][r] + bias[n0 + nt * 16 + lr];
}

// ---------------------------------------------------------------------------
// Attention v5: Q-tile 64, 4 qt/wave, kt split across 2 blocks (grid 1024).
// __launch_bounds__(256,3): observed allocator mapping arg->cap {2:128,
// 3:~170, 4:64}; (256,4) force-spilled (round 7: 689MB FETCH of scratch).
// Body identical to the proven round-5 loop (scalar f16 converts; compiler
// fuses to v_cvt_pkrtz). exp2-no-max softmax => split partials combine
// linearly in `combine`.
// ---------------------------------------------------------------------------
__global__ __launch_bounds__(256, 3) void attn_kernel(
    const bf16* __restrict__ Q, const bf16* __restrict__ Kmat,
    const _Float16* __restrict__ Vt, float* __restrict__ AOp,
    float* __restrict__ Lp)
{
    __shared__ __align__(16) float cbuf[2][4][4][64][4];  // 32 KB
    __shared__ float lbuf[4][4][16];                      // 1 KB

    const int h = blockIdx.x & 7;
    const int s = (blockIdx.x >> 3) & 1;
    const int qb = blockIdx.x >> 4;
    const int t = threadIdx.x, lane = t & 63, w = t >> 6;
    const int lr = lane & 15, lq = lane >> 4;
    const int q0 = qb * 64;

    // Q B-frags for 4 qt tiles (B[n=lr][k=lq*8+j])
    bf16x8 qf[4][2];
    #pragma unroll
    for (int qt = 0; qt < 4; ++qt) {
        const bf16* qp = Q + (size_t)(q0 + qt * 16 + lr) * DMODEL + h * HDIM + lq * 8;
        qf[qt][0] = *(const bf16x8*)qp;
        qf[qt][1] = *(const bf16x8*)(qp + 32);
    }

    // incremented pointers: K per mt, V per ht
    const int kt0 = w + 32 * s;
    const bf16* kp[4];
    const _Float16* vp[4];
    #pragma unroll
    for (int mt = 0; mt < 4; ++mt)
        kp[mt] = Kmat + (size_t)(kt0 * 64 + mt * 16 + lr) * DMODEL + h * HDIM + lq * 8;
    #pragma unroll
    for (int ht = 0; ht < 4; ++ht)
        vp[ht] = Vt + (size_t)(h * HDIM + ht * 16 + lr) * S_LEN + kt0 * 64 + lq * 4;
    const size_t kstep = (size_t)4 * 64 * DMODEL;   // 4 kt tiles of rows
    const size_t vstep = 4 * 64;                    // 4 kt tiles of cols

    f32x4 oacc[4][4];   // [qt][ht]; C: row(Q)=lq*4+r, col(hd)=lr
    #pragma unroll
    for (int i = 0; i < 4; ++i)
        #pragma unroll
        for (int j = 0; j < 4; ++j) oacc[i][j] = f32x4{0, 0, 0, 0};
    float lsum[4] = {0, 0, 0, 0};

    for (int i = 0; i < 8; ++i) {
        // K A-frags (A[m=lr][k=lq*8+j])
        bf16x8 kf[4][2];
        #pragma unroll
        for (int mt = 0; mt < 4; ++mt) {
            kf[mt][0] = *(const bf16x8*)kp[mt];
            kf[mt][1] = *(const bf16x8*)(kp[mt] + 32);
        }
        // V^T B-frags (B[n=hd=lr][k=Kidx=lq*4+j])
        f16x4 vf[4][4];   // [mt][ht]
        #pragma unroll
        for (int ht = 0; ht < 4; ++ht)
            #pragma unroll
            for (int mt = 0; mt < 4; ++mt)
                vf[mt][ht] = *(const f16x4*)(vp[ht] + mt * 16);

        #pragma unroll
        for (int qt = 0; qt < 4; ++qt) {
            f32x4 st[4];
            #pragma unroll
            for (int mt = 0; mt < 4; ++mt) {
                f32x4 z = {0, 0, 0, 0};
                z = mfma16x16x32(kf[mt][0], qf[qt][0], z);
                z = mfma16x16x32(kf[mt][1], qf[qt][1], z);
                st[mt] = z;
            }
            // P = exp2(S^T); A-frag of 16x16x16: A[m=Q=lr][k=lq*4+r]
            f16x4 pf[4];
            #pragma unroll
            for (int mt = 0; mt < 4; ++mt)
                #pragma unroll
                for (int r = 0; r < 4; ++r) {
                    float p = exp2f(st[mt][r]);
                    lsum[qt] += p;
                    pf[mt][r] = (_Float16)p;
                }
            #pragma unroll
            for (int mt = 0; mt < 4; ++mt)
                #pragma unroll
                for (int ht = 0; ht < 4; ++ht)
                    oacc[qt][ht] = mfma16x16x16h(pf[mt], vf[mt][ht], oacc[qt][ht]);
        }

        #pragma unroll
        for (int mt = 0; mt < 4; ++mt) kp[mt] += kstep;
        #pragma unroll
        for (int ht = 0; ht < 4; ++ht) vp[ht] += vstep;
    }

    // ---- l partials: reduce over lq groups, publish ----
    #pragma unroll
    for (int qt = 0; qt < 4; ++qt) {
        float v = lsum[qt];
        v += __shfl_xor(v, 16);
        v += __shfl_xor(v, 32);
        if (lq == 0) lbuf[w][qt][lr] = v;
    }

    // ---- 3-round rotating O exchange: wave w ends owning qt == w ----
    #pragma unroll
    for (int r = 1; r < 4; ++r) {
        int src = (w + r) & 3;
        #pragma unroll
        for (int ht = 0; ht < 4; ++ht)
            *(f32x4*)&cbuf[r & 1][w][ht][lane][0] = oacc[src][ht];
        __syncthreads();
        int from = (w - r) & 3;
        #pragma unroll
        for (int ht = 0; ht < 4; ++ht)
            oacc[w][ht] += *(const f32x4*)&cbuf[r & 1][from][ht][lane][0];
    }

    // ---- store split-partial O (f32) + split-partial l ----
    float* aop = AOp + (size_t)s * S_LEN * DMODEL;
    #pragma unroll
    for (int r = 0; r < 4; ++r) {
        int row = q0 + w * 16 + lq * 4 + r;
        #pragma unroll
        for (int ht = 0; ht < 4; ++ht)
            aop[(size_t)row * DMODEL + h * HDIM + ht * 16 + lr] = oacc[w][ht][r];
    }
    if (lq == 0) {
        float lt = lbuf[0][w][lr] + lbuf[1][w][lr] + lbuf[2][w][lr] + lbuf[3][w][lr];
        Lp[(size_t)s * NHEADS * S_LEN + (size_t)h * S_LEN + q0 + w * 16 + lr] = lt;
    }
}

// ---------------------------------------------------------------------------
// Combine the two kt-splits: AO = bf16( (O0+O1) / (l0+l1) )
// ---------------------------------------------------------------------------
__global__ __launch_bounds__(256) void combine(
    const float* __restrict__ AOp, const float* __restrict__ Lp,
    bf16* __restrict__ AO)
{
    int i = (blockIdx.x * 256 + threadIdx.x) * 8;
    int row = i >> 9, col = i & 511, h = col >> 6;
    float l0 = Lp[(size_t)h * S_LEN + row];
    float l1 = Lp[(size_t)NHEADS * S_LEN + (size_t)h * S_LEN + row];
    float linv = 1.0f / (l0 + l1);
    const float* p0 = AOp + i;
    const float* p1 = AOp + (size_t)S_LEN * DMODEL + i;
    float4 a0 = *(const float4*)p0;
    float4 a1 = *(const float4*)(p0 + 4);
    float4 b0 = *(const float4*)p1;
    float4 b1 = *(const float4*)(p1 + 4);
    bf16 tmp[8];
    tmp[0] = __float2bfloat16((a0.x + b0.x) * linv);
    tmp[1] = __float2bfloat16((a0.y + b0.y) * linv);
    tmp[2] = __float2bfloat16((a0.z + b0.z) * linv);
    tmp[3] = __float2bfloat16((a0.w + b0.w) * linv);
    tmp[4] = __float2bfloat16((a1.x + b1.x) * linv);
    tmp[5] = __float2bfloat16((a1.y + b1.y) * linv);
    tmp[6] = __float2bfloat16((a1.z + b1.z) * linv);
    tmp[7] = __float2bfloat16((a1.w + b1.w) * linv);
    *(bf16x8*)(AO + i) = *(bf16x8*)tmp;
}

// ---------------------------------------------------------------------------
extern "C" void kernel_launch(void* const* d_in, const int* in_sizes, int n_in,
                              void* d_out, int out_size, void* d_ws, size_t ws_size,
                              hipStream_t stream) {
    const float* X  = (const float*)d_in[0];
    const float* Wq = (const float*)d_in[1];
    const float* Wk = (const float*)d_in[2];
    const float* Wv = (const float*)d_in[3];
    const float* Wo = (const float*)d_in[4];
    const float* bo = (const float*)d_in[5];
    float* out = (float*)d_out;

    char* ws = (char*)d_ws;
    bf16* Wt = (bf16*)ws;                                  // [4][512][512] bf16
    bf16* Xb = (bf16*)(ws + (size_t)4 * DMODEL * DMODEL * 2);
    bf16* Qm = Xb + (size_t)S_LEN * DMODEL;
    bf16* Km = Qm + (size_t)S_LEN * DMODEL;
    _Float16* Vt = (_Float16*)(Km + (size_t)S_LEN * DMODEL);   // [512][4096] f16
    bf16* AO = (bf16*)(Vt + (size_t)S_LEN * DMODEL);
    float* AOp = (float*)(AO + (size_t)S_LEN * DMODEL);        // [2][4096][512] f32
    float* Lp  = AOp + (size_t)2 * S_LEN * DMODEL;             // [2][8][4096] f32

    bf16* Wot = Wt + (size_t)3 * DMODEL * DMODEL;

    int nX = S_LEN * DMODEL;
    cvt_f32_bf16<<<nX / (256 * 8), 256, 0, stream>>>(X, Xb, nX);
    transpose_w<<<dim3(16, 16, 4), dim3(32, 8), 0, stream>>>(Wq, Wk, Wv, Wo, Wt);

    gemm_qkv<<<dim3(S_LEN / 64, 3 * DMODEL / 64), 256, 0, stream>>>(
        Xb, Wt, Qm, Km, Vt);

    attn_kernel<<<1024, 256, 0, stream>>>(Qm, Km, Vt, AOp, Lp);
    combine<<<S_LEN * DMODEL / (256 * 8), 256, 0, stream>>>(AOp, Lp, AO);

    gemm_out<<<dim3(S_LEN / 64, DMODEL / 64), 256, 0, stream>>>(AO, Wot, out, bo);
}